// Round 1
// baseline (130.781 us; speedup 1.0000x reference)
//
#include <hip/hip_runtime.h>

#define BATCH 8192
#define INC   512
#define OUTC  512
#define NB    8
#define KDIM  (INC * NB)   // 4096

#define BM 64
#define BN 128
#define BK 64
#define NKT (KDIM / BK)    // 64
#define LDA 72             // A row stride in shorts (64 + 8 pad), 144 B
#define THREADS 256

typedef __attribute__((ext_vector_type(8))) short bf16x8;
typedef __attribute__((ext_vector_type(4))) float f32x4;
typedef __attribute__((ext_vector_type(4))) int   i32x4;

// truncate-pack two fp32 into two bf16 (lo -> low 16 bits) in one v_perm_b32
static __device__ __forceinline__ unsigned int pk2(float lo, float hi) {
    return __builtin_amdgcn_perm(__builtin_bit_cast(unsigned int, hi),
                                 __builtin_bit_cast(unsigned int, lo),
                                 0x07060302u);
}

// ---- prepass: W fp32 -> bf16 (RNE) into workspace ----
__global__ __launch_bounds__(256)
void w_prepass(const float* __restrict__ W, unsigned short* __restrict__ Wb) {
    const int base = (blockIdx.x * 256 + threadIdx.x) * 8;
    const float4 a = *(const float4*)(W + base);
    const float4 b = *(const float4*)(W + base + 4);
    const float v[8] = {a.x, a.y, a.z, a.w, b.x, b.y, b.z, b.w};
    unsigned int r[8];
#pragma unroll
    for (int i = 0; i < 8; ++i) {
        unsigned int t = __builtin_bit_cast(unsigned int, v[i]);
        t += 0x7FFFu + ((t >> 16) & 1u);   // round-to-nearest-even
        r[i] = t >> 16;
    }
    i32x4 out = {(int)(r[0] | (r[1] << 16)), (int)(r[2] | (r[3] << 16)),
                 (int)(r[4] | (r[5] << 16)), (int)(r[6] | (r[7] << 16))};
    *(i32x4*)(Wb + base) = out;
}

// B LDS layout (swizzled to kill bank conflicts on ds_read_b128):
//   element (row 0..127, kblk 0..7)  [kblk = 8-short group of the 64-wide k slab]
//   lives at short offset: row*64 + (kblk ^ (row & 7)) * 8
// DMA realizes this by permuting the GLOBAL k-block each lane fetches.
//
// Pipeline (this revision): double-buffered As/Bs, ONE barrier per k-tile.
//   iter kt: { issue DMA B(kt+1)->buf^1 ; basis(kt+1)->buf^1 ; MFMA(buf) ; sync }
// so the barrier's vmcnt drain waits on loads issued a full phase earlier.

template <bool DMA>
__global__ __launch_bounds__(THREADS, 2)
void tanh_basis_fused_gemm(const float* __restrict__ X,    // (BATCH, INC)
                           const void*  __restrict__ Wsrc, // (OUTC, KDIM)
                           const float* __restrict__ CEN,  // (INC, NB) rows identical
                           const float* __restrict__ SLP,  // (INC, NB) rows identical
                           float* __restrict__ Y)          // (BATCH, OUTC)
{
    __shared__ short As[2][BM][LDA];   // 2 * 9216 B
    __shared__ short Bs[2][BN * BK];   // 2 * 16384 B  (swizzled)

    const int tid  = threadIdx.x;
    const int lane = tid & 63;
    const int wave = tid >> 6;     // 0..3
    const int wm   = wave & 1;     // m-wave: rows of 32
    const int wn   = wave >> 1;    // n-wave: cols of 64

    const int b0 = blockIdx.x * BM;
    const int j0 = blockIdx.y * BN;

    // basis: s_m(x) = 1/(1 + exp2(g2*(c_m - x))), g2 = 2*gamma*log2(e)
    // centers are a linspace, slopes uniform -> e_m = e_0 * R^m
    const float L2E = 1.4426950408889634f;
    const float g2  = 2.0f * SLP[0] * L2E;
    const float pc  = -g2;
    const float q0  = g2 * CEN[0];
    const float R   = __builtin_amdgcn_exp2f(g2 * (CEN[1] - CEN[0]));

    // A staging role: thread -> (row, 2 consecutive i-slots of the 8-wide i-slab)
    const int arow = tid >> 2;          // 0..63
    const int acol = (tid & 3) * 2;     // 0,2,4,6
    const float* xp = X + (size_t)(b0 + arow) * INC + acol;

    f32x4 acc[2][4];
#pragma unroll
    for (int i = 0; i < 2; ++i)
#pragma unroll
        for (int j = 0; j < 4; ++j)
            acc[i][j] = (f32x4){0.f, 0.f, 0.f, 0.f};

    // fragment read offsets (within one buffer)
    const int aoff = (wm * 32 + (lane & 15)) * LDA + (lane >> 4) * 8;
    const int brow = wn * 64 + (lane & 15);          // B row for this lane
    const int low3 = lane & 7;                       // == brow & 7
    const int h    = lane >> 4;                      // 0..3
    const int boff0 = brow * BK + ((h)     ^ low3) * 8; // ks=0
    const int boff1 = brow * BK + ((4 + h) ^ low3) * 8; // ks=1

    // DMA global-side swizzle (per-lane, hoisted out of k-loop)
    const int dma_r    = lane >> 3;                    // row within 8-row chunk
    const int dma_kblk = (lane & 7) ^ dma_r;           // permuted k-block

    // ---- staging helpers ----
    auto stage_B = [&](int kt, int buf) {
        if constexpr (DMA) {
            const unsigned short* Wb = (const unsigned short*)Wsrc;
#pragma unroll
            for (int q = 0; q < 4; ++q) {
                const int cc = wave * 4 + q;   // 1 KB chunk id, wave-uniform
                const unsigned short* gp = Wb
                    + (size_t)(j0 + cc * 8 + dma_r) * KDIM
                    + kt * BK + dma_kblk * 8;
                __builtin_amdgcn_global_load_lds(
                    (const __attribute__((address_space(1))) void*)gp,
                    (__attribute__((address_space(3))) void*)(&Bs[buf][cc * 512]),
                    16, 0, 0);
            }
        } else {
            const float* Wf = (const float*)Wsrc;
            const int frow = tid >> 1;     // 0..127
            const int fkh  = tid & 1;      // which 32-float half (kblks 4*fkh..4*fkh+3)
            const float* wp = Wf + (size_t)(j0 + frow) * KDIM + kt * BK + fkh * 32;
            float4 cv[8];
#pragma unroll
            for (int q = 0; q < 8; ++q) cv[q] = ((const float4*)wp)[q];
#pragma unroll
            for (int kb = 0; kb < 4; ++kb) {
                const int kblk = fkh * 4 + kb;
                i32x4* bw = (i32x4*)(&Bs[buf][frow * BK + ((kblk ^ (frow & 7)) * 8)]);
                *bw = (i32x4){(int)pk2(cv[2*kb].x, cv[2*kb].y),
                              (int)pk2(cv[2*kb].z, cv[2*kb].w),
                              (int)pk2(cv[2*kb+1].x, cv[2*kb+1].y),
                              (int)pk2(cv[2*kb+1].z, cv[2*kb+1].w)};
            }
        }
    };

    auto stage_A = [&](float2 xq, int buf) {
        float e = __builtin_amdgcn_exp2f(fmaf(pc, xq.x, q0));
        float s[NB];
#pragma unroll
        for (int m = 0; m < NB; ++m) {
            s[m] = __builtin_amdgcn_rcpf(1.0f + e);
            e *= R;
        }
        *(i32x4*)(&As[buf][arow][acol * 8]) =
            (i32x4){(int)pk2(s[0], s[1]), (int)pk2(s[2], s[3]),
                    (int)pk2(s[4], s[5]), (int)pk2(s[6], s[7])};

        e = __builtin_amdgcn_exp2f(fmaf(pc, xq.y, q0));
#pragma unroll
        for (int m = 0; m < NB; ++m) {
            s[m] = __builtin_amdgcn_rcpf(1.0f + e);
            e *= R;
        }
        *(i32x4*)(&As[buf][arow][(acol + 1) * 8]) =
            (i32x4){(int)pk2(s[0], s[1]), (int)pk2(s[2], s[3]),
                    (int)pk2(s[4], s[5]), (int)pk2(s[6], s[7])};
    };

    // ---- prologue: stage tile 0 into buffer 0 ----
    float2 xv = *(const float2*)(xp);          // x for tile 0
    stage_B(0, 0);
    stage_A(xv, 0);
    xv = *(const float2*)(xp + NB);            // x for tile 1
    __syncthreads();                           // tile 0 resident

    for (int kt = 0; kt < NKT; ++kt) {
        const int cb = kt & 1;
        const int nb = cb ^ 1;

        // ---- stage tile kt+1 into the other buffer (overlaps MFMA below) ----
        if (kt + 1 < NKT) {
            stage_B(kt + 1, nb);
            stage_A(xv, nb);
            const int ktn2 = (kt + 2 < NKT) ? (kt + 2) : (NKT - 1);
            xv = *(const float2*)(xp + ktn2 * NB);
        }

        // ---- MFMA on tile kt ----
        const short* abase = &As[cb][0][0];
        const short* bbase = &Bs[cb][0];
#pragma unroll
        for (int ks = 0; ks < 2; ++ks) {
            const int boffk = ks ? boff1 : boff0;
            bf16x8 af[2], bfr[4];
#pragma unroll
            for (int mf = 0; mf < 2; ++mf)
                af[mf] = *(const bf16x8*)(abase + aoff + mf * 16 * LDA + ks * 32);
#pragma unroll
            for (int nf = 0; nf < 4; ++nf)
                bfr[nf] = *(const bf16x8*)(bbase + boffk + nf * 16 * BK);
#pragma unroll
            for (int mf = 0; mf < 2; ++mf)
#pragma unroll
                for (int nf = 0; nf < 4; ++nf)
                    acc[mf][nf] = __builtin_amdgcn_mfma_f32_16x16x32_bf16(
                        af[mf], bfr[nf], acc[mf][nf], 0, 0, 0);
        }

        // one barrier per tile: drains DMA+ds_writes for tile kt+1 (issued
        // before the MFMAs above) and fences this tile's reads before the
        // next iteration overwrites buffer cb.
        __syncthreads();
    }

    // ---- epilogue: C/D layout col=lane&15, row=(lane>>4)*4+reg ----
    const int lm = (lane >> 4) * 4;
    const int ln = lane & 15;
    const int rowb = b0 + wm * 32 + lm;
    const int colb = j0 + wn * 64 + ln;
#pragma unroll
    for (int mf = 0; mf < 2; ++mf)
#pragma unroll
        for (int nf = 0; nf < 4; ++nf)
#pragma unroll
            for (int r = 0; r < 4; ++r)
                Y[(size_t)(rowb + mf * 16 + r) * OUTC + (colb + nf * 16)] = acc[mf][nf][r];
}

extern "C" void kernel_launch(void* const* d_in, const int* in_sizes, int n_in,
                              void* d_out, int out_size, void* d_ws, size_t ws_size,
                              hipStream_t stream) {
    const float* X   = (const float*)d_in[0];
    const float* W   = (const float*)d_in[1];
    const float* CEN = (const float*)d_in[2];
    const float* SLP = (const float*)d_in[3];
    float* Y = (float*)d_out;

    static_assert(BATCH % BM == 0 && OUTC % BN == 0 && KDIM % BK == 0, "tiling");
    dim3 grid(BATCH / BM, OUTC / BN);   // 128 x 4 = 512 blocks

    const size_t WB_BYTES = (size_t)OUTC * KDIM * sizeof(unsigned short); // 4 MB
    if (ws_size >= WB_BYTES) {
        w_prepass<<<dim3((OUTC * KDIM) / (8 * 256)), dim3(256), 0, stream>>>(
            W, (unsigned short*)d_ws);
        tanh_basis_fused_gemm<true><<<grid, dim3(THREADS), 0, stream>>>(
            X, d_ws, CEN, SLP, Y);
    } else {
        tanh_basis_fused_gemm<false><<<grid, dim3(THREADS), 0, stream>>>(
            X, (const void*)W, CEN, SLP, Y);
    }
}

// Round 2
// 122.855 us; speedup vs baseline: 1.0645x; 1.0645x over previous
//
#include <hip/hip_runtime.h>

#define BATCH 8192
#define INC   512
#define OUTC  512
#define NB    8
#define KDIM  (INC * NB)   // 4096

#define BM 64
#define BN 128
#define BK 64
#define NKT (KDIM / BK)    // 64
#define LDA 72             // A row stride in shorts (64 + 8 pad), 144 B
#define THREADS 256

typedef __attribute__((ext_vector_type(8))) short bf16x8;
typedef __attribute__((ext_vector_type(4))) float f32x4;
typedef __attribute__((ext_vector_type(4))) int   i32x4;

// truncate-pack two fp32 into two bf16 (lo -> low 16 bits) in one v_perm_b32
static __device__ __forceinline__ unsigned int pk2(float lo, float hi) {
    return __builtin_amdgcn_perm(__builtin_bit_cast(unsigned int, hi),
                                 __builtin_bit_cast(unsigned int, lo),
                                 0x07060302u);
}

// ---- prepass: W fp32 -> bf16 (RNE) into workspace ----
__global__ __launch_bounds__(256)
void w_prepass(const float* __restrict__ W, unsigned short* __restrict__ Wb) {
    const int base = (blockIdx.x * 256 + threadIdx.x) * 8;
    const float4 a = *(const float4*)(W + base);
    const float4 b = *(const float4*)(W + base + 4);
    const float v[8] = {a.x, a.y, a.z, a.w, b.x, b.y, b.z, b.w};
    unsigned int r[8];
#pragma unroll
    for (int i = 0; i < 8; ++i) {
        unsigned int t = __builtin_bit_cast(unsigned int, v[i]);
        t += 0x7FFFu + ((t >> 16) & 1u);   // round-to-nearest-even
        r[i] = t >> 16;
    }
    i32x4 out = {(int)(r[0] | (r[1] << 16)), (int)(r[2] | (r[3] << 16)),
                 (int)(r[4] | (r[5] << 16)), (int)(r[6] | (r[7] << 16))};
    *(i32x4*)(Wb + base) = out;
}

// B LDS layout (swizzled to kill bank conflicts on ds_read_b128):
//   element (row 0..127, kblk 0..7) lives at short offset:
//   row*64 + (kblk ^ (row & 7)) * 8
// DMA realizes this by permuting the GLOBAL k-block each lane fetches.
//
// Pipeline (round 2): double-buffered As/Bs with COUNTED vmcnt + raw
// s_barrier (T3/T4). Per-step vm issue order is [x-load, DMA x4] = 5 ops;
// "s_waitcnt vmcnt(5)" before barrier #1 guarantees the PREVIOUS step's
// DMA (one full k-tile old) has landed while this step's 5 stay in flight.
// vmcnt is never drained to 0 in the main loop.

template <bool DMA>
__global__ __launch_bounds__(THREADS, 2)
void tanh_basis_fused_gemm(const float* __restrict__ X,    // (BATCH, INC)
                           const void*  __restrict__ Wsrc, // (OUTC, KDIM)
                           const float* __restrict__ CEN,  // (INC, NB) rows identical
                           const float* __restrict__ SLP,  // (INC, NB) rows identical
                           float* __restrict__ Y)          // (BATCH, OUTC)
{
    __shared__ short As[2][BM][LDA];   // 2 * 9216 B
    __shared__ short Bs[2][BN * BK];   // 2 * 16384 B  (swizzled)

    const int tid  = threadIdx.x;
    const int lane = tid & 63;
    const int wave = tid >> 6;     // 0..3
    const int wm   = wave & 1;     // m-wave: rows of 32
    const int wn   = wave >> 1;    // n-wave: cols of 64

    const int b0 = blockIdx.x * BM;
    const int j0 = blockIdx.y * BN;

    // basis: s_m(x) = 1/(1 + exp2(g2*(c_m - x))), g2 = 2*gamma*log2(e)
    // centers are a linspace, slopes uniform -> e_m = e_0 * R^m
    const float L2E = 1.4426950408889634f;
    const float g2  = 2.0f * SLP[0] * L2E;
    const float pc  = -g2;
    const float q0  = g2 * CEN[0];
    const float R   = __builtin_amdgcn_exp2f(g2 * (CEN[1] - CEN[0]));

    // A staging role: thread -> (row, 2 consecutive i-slots of the 8-wide i-slab)
    const int arow = tid >> 2;          // 0..63
    const int acol = (tid & 3) * 2;     // 0,2,4,6
    const float* xp = X + (size_t)(b0 + arow) * INC + acol;

    f32x4 acc[2][4];
#pragma unroll
    for (int i = 0; i < 2; ++i)
#pragma unroll
        for (int j = 0; j < 4; ++j)
            acc[i][j] = (f32x4){0.f, 0.f, 0.f, 0.f};

    // fragment read offsets (within one buffer)
    const int aoff = (wm * 32 + (lane & 15)) * LDA + (lane >> 4) * 8;
    const int brow = wn * 64 + (lane & 15);          // B row for this lane
    const int low3 = lane & 7;                       // == brow & 7
    const int h    = lane >> 4;                      // 0..3
    const int boff0 = brow * BK + ((h)     ^ low3) * 8; // ks=0
    const int boff1 = brow * BK + ((4 + h) ^ low3) * 8; // ks=1

    // DMA global-side swizzle (per-lane, hoisted out of k-loop)
    const int dma_r    = lane >> 3;                    // row within 8-row chunk
    const int dma_kblk = (lane & 7) ^ dma_r;           // permuted k-block

    // ---- staging helpers ----
    auto stage_B = [&](int kt, short* bs) {
        if constexpr (DMA) {
            const unsigned short* Wb = (const unsigned short*)Wsrc;
#pragma unroll
            for (int q = 0; q < 4; ++q) {
                const int cc = wave * 4 + q;   // 1 KB chunk id, wave-uniform
                const unsigned short* gp = Wb
                    + (size_t)(j0 + cc * 8 + dma_r) * KDIM
                    + kt * BK + dma_kblk * 8;
                __builtin_amdgcn_global_load_lds(
                    (const __attribute__((address_space(1))) void*)gp,
                    (__attribute__((address_space(3))) void*)(bs + cc * 512),
                    16, 0, 0);
            }
        } else {
            const float* Wf = (const float*)Wsrc;
            const int frow = tid >> 1;     // 0..127
            const int fkh  = tid & 1;      // which 32-float half
            const float* wp = Wf + (size_t)(j0 + frow) * KDIM + kt * BK + fkh * 32;
            float4 cv[8];
#pragma unroll
            for (int q = 0; q < 8; ++q) cv[q] = ((const float4*)wp)[q];
#pragma unroll
            for (int kb = 0; kb < 4; ++kb) {
                const int kblk = fkh * 4 + kb;
                i32x4* bw = (i32x4*)(bs + frow * BK + ((kblk ^ (frow & 7)) * 8));
                *bw = (i32x4){(int)pk2(cv[2*kb].x, cv[2*kb].y),
                              (int)pk2(cv[2*kb].z, cv[2*kb].w),
                              (int)pk2(cv[2*kb+1].x, cv[2*kb+1].y),
                              (int)pk2(cv[2*kb+1].z, cv[2*kb+1].w)};
            }
        }
    };

    auto stage_A = [&](float2 xq, short* as_base) {
        float e = __builtin_amdgcn_exp2f(fmaf(pc, xq.x, q0));
        float s[NB];
#pragma unroll
        for (int m = 0; m < NB; ++m) {
            s[m] = __builtin_amdgcn_rcpf(1.0f + e);
            e *= R;
        }
        *(i32x4*)(as_base + arow * LDA + acol * 8) =
            (i32x4){(int)pk2(s[0], s[1]), (int)pk2(s[2], s[3]),
                    (int)pk2(s[4], s[5]), (int)pk2(s[6], s[7])};

        e = __builtin_amdgcn_exp2f(fmaf(pc, xq.y, q0));
#pragma unroll
        for (int m = 0; m < NB; ++m) {
            s[m] = __builtin_amdgcn_rcpf(1.0f + e);
            e *= R;
        }
        *(i32x4*)(as_base + arow * LDA + (acol + 1) * 8) =
            (i32x4){(int)pk2(s[0], s[1]), (int)pk2(s[2], s[3]),
                    (int)pk2(s[4], s[5]), (int)pk2(s[6], s[7])};
    };

    auto mfma_tile = [&](const short* abase, const short* bbase) {
#pragma unroll
        for (int ks = 0; ks < 2; ++ks) {
            const int boffk = ks ? boff1 : boff0;
            bf16x8 af[2], bfr[4];
#pragma unroll
            for (int mf = 0; mf < 2; ++mf)
                af[mf] = *(const bf16x8*)(abase + aoff + mf * 16 * LDA + ks * 32);
#pragma unroll
            for (int nf = 0; nf < 4; ++nf)
                bfr[nf] = *(const bf16x8*)(bbase + boffk + nf * 16 * BK);
#pragma unroll
            for (int mf = 0; mf < 2; ++mf)
#pragma unroll
                for (int nf = 0; nf < 4; ++nf)
                    acc[mf][nf] = __builtin_amdgcn_mfma_f32_16x16x32_bf16(
                        af[mf], bfr[nf], acc[mf][nf], 0, 0, 0);
        }
    };

    // ---- prologue: vm order [x0, x1, DMA(tile0) x4]; basis tile0 -> buf0 ----
    float2 xv = *(const float2*)(xp);          // x for tile 0
    float2 xn = *(const float2*)(xp + NB);     // x for tile 1
    stage_B(0, &Bs[0][0]);
    stage_A(xv, &As[0][0][0]);
    xv = xn;

    // Per step KT: stage tile KT+1 into NXT, MFMA tile KT from CUR.
    // vm order per step: [x(KT+2), DMA(KT+1) x4] = 5 ops -> vmcnt(5) keeps
    // exactly this step's loads in flight and drains everything older.
#define STEP(KT, CUR, NXT)                                                   \
    {                                                                        \
        const int kt_ = (KT);                                                \
        const int kx_ = (kt_ + 2 < NKT) ? kt_ + 2 : NKT - 1;                 \
        const int kb_ = (kt_ + 1 < NKT) ? kt_ + 1 : NKT - 1;                 \
        xn = *(const float2*)(xp + kx_ * NB);                                \
        stage_B(kb_, &Bs[NXT][0]);                                           \
        stage_A(xv, &As[NXT][0][0]);                                         \
        __builtin_amdgcn_sched_barrier(0);                                   \
        asm volatile("s_waitcnt vmcnt(5) lgkmcnt(0)" ::: "memory");          \
        __builtin_amdgcn_s_barrier();                                        \
        __builtin_amdgcn_sched_barrier(0);                                   \
        __builtin_amdgcn_s_setprio(1);                                       \
        mfma_tile(&As[CUR][0][0], &Bs[CUR][0]);                              \
        __builtin_amdgcn_s_setprio(0);                                       \
        __builtin_amdgcn_sched_barrier(0);                                   \
        __builtin_amdgcn_s_barrier();                                        \
        __builtin_amdgcn_sched_barrier(0);                                   \
        xv = xn;                                                             \
    }

    for (int kt2 = 0; kt2 < NKT; kt2 += 2) {
        STEP(kt2,     0, 1);
        STEP(kt2 + 1, 1, 0);
    }
#undef STEP

    // drain the tail staging DMAs before LDS goes away / stores issue
    asm volatile("s_waitcnt vmcnt(0) lgkmcnt(0)" ::: "memory");

    // ---- epilogue: C/D layout col=lane&15, row=(lane>>4)*4+reg ----
    const int lm = (lane >> 4) * 4;
    const int ln = lane & 15;
    const int rowb = b0 + wm * 32 + lm;
    const int colb = j0 + wn * 64 + ln;
#pragma unroll
    for (int mf = 0; mf < 2; ++mf)
#pragma unroll
        for (int nf = 0; nf < 4; ++nf)
#pragma unroll
            for (int r = 0; r < 4; ++r)
                Y[(size_t)(rowb + mf * 16 + r) * OUTC + (colb + nf * 16)] = acc[mf][nf][r];
}

extern "C" void kernel_launch(void* const* d_in, const int* in_sizes, int n_in,
                              void* d_out, int out_size, void* d_ws, size_t ws_size,
                              hipStream_t stream) {
    const float* X   = (const float*)d_in[0];
    const float* W   = (const float*)d_in[1];
    const float* CEN = (const float*)d_in[2];
    const float* SLP = (const float*)d_in[3];
    float* Y = (float*)d_out;

    static_assert(BATCH % BM == 0 && OUTC % BN == 0 && KDIM % BK == 0, "tiling");
    dim3 grid(BATCH / BM, OUTC / BN);   // 128 x 4 = 512 blocks

    const size_t WB_BYTES = (size_t)OUTC * KDIM * sizeof(unsigned short); // 4 MB
    if (ws_size >= WB_BYTES) {
        w_prepass<<<dim3((OUTC * KDIM) / (8 * 256)), dim3(256), 0, stream>>>(
            W, (unsigned short*)d_ws);
        tanh_basis_fused_gemm<true><<<grid, dim3(THREADS), 0, stream>>>(
            X, d_ws, CEN, SLP, Y);
    } else {
        tanh_basis_fused_gemm<false><<<grid, dim3(THREADS), 0, stream>>>(
            X, (const void*)W, CEN, SLP, Y);
    }
}